// Round 6
// baseline (3255.159 us; speedup 1.0000x reference)
//
#include <hip/hip_runtime.h>
#include <hip/hip_bf16.h>
#include <math.h>

#define SEQ 512
#define NB  64
#define NIN 512
#define NH  1024
#define NO  512

#define SPIN_LIM 20000  // bounded waits -> visible FAIL, never a watchdog hang

typedef __bf16 bf16x8 __attribute__((ext_vector_type(8)));
typedef float  f32x4  __attribute__((ext_vector_type(4)));
typedef unsigned int u32x4 __attribute__((ext_vector_type(4)));

__device__ __forceinline__ f32x4 mfma16(bf16x8 a, bf16x8 b, f32x4 c) {
  return __builtin_amdgcn_mfma_f32_16x16x32_bf16(a, b, c, 0, 0, 0);
}

// ---- exchange: agent-scope tag-in-data (R5-PROVEN protocol) ----
// Board word = hi bf16 [31:16] | lo bf16 top-13 [15:3] | tag [2:0].
// tag(h_s) = (s+2)&7. Single-u32 atomicity => the poll IS the data read: no
// acks, no flags, no fences. Producer: relaxed AGENT atomic store (proven
// cross-CU visible). Consumer: volatile loads (re-issued per round; per-word
// tag validates per-word). Poison 0xAA (tag 2) rejects at first uses; depth-2
// parity reuse is WAR-safe by full-team step gating (a WG publishes h_{t+1}
// only after consuming ALL of h_t into registers).
//
// R6 change: per-chunk incremental consume. Wave wv's chunk c (8 u32/lane)
// is produced by exactly ONE WG (r' = 8*wv + c), so chunks gate independently.

// check chunk c of q[]: all 8 words carry tag TEXP (wave-uniform result)
#define CHUNK_CHECK(c, TEXP, ok)                                               \
  {                                                                            \
    unsigned int bad = 0;                                                      \
    u32x4 va = q[2 * (c)], vb = q[2 * (c) + 1];                                \
    bad |= (va[0] ^ (TEXP)) | (va[1] ^ (TEXP)) | (va[2] ^ (TEXP)) |            \
           (va[3] ^ (TEXP));                                                   \
    bad |= (vb[0] ^ (TEXP)) | (vb[1] ^ (TEXP)) | (vb[2] ^ (TEXP)) |            \
           (vb[3] ^ (TEXP));                                                   \
    ok = __all((bad & 7u) == 0);                                               \
  }

// unpack chunk c (hi|lo planes) and run its 6 h-MFMAs + 2 o-MFMAs
#define CONSUME(c)                                                             \
  {                                                                            \
    u32x4 a = q[2 * (c)], b = q[2 * (c) + 1];                                  \
    u32x4 hw, lw;                                                              \
    hw[0] = (a[0] >> 16) | (a[1] & 0xFFFF0000u);                               \
    hw[1] = (a[2] >> 16) | (a[3] & 0xFFFF0000u);                               \
    hw[2] = (b[0] >> 16) | (b[1] & 0xFFFF0000u);                               \
    hw[3] = (b[2] >> 16) | (b[3] & 0xFFFF0000u);                               \
    lw[0] = ((a[0] & 0xFFFFu) | (a[1] << 16)) & 0xFFF8FFF8u;                   \
    lw[1] = ((a[2] & 0xFFFFu) | (a[3] << 16)) & 0xFFF8FFF8u;                   \
    lw[2] = ((b[0] & 0xFFFFu) | (b[1] << 16)) & 0xFFF8FFF8u;                   \
    lw[3] = ((b[2] & 0xFFFFu) | (b[3] << 16)) & 0xFFF8FFF8u;                   \
    bf16x8 ahi = __builtin_bit_cast(bf16x8, hw);                               \
    bf16x8 alo = __builtin_bit_cast(bf16x8, lw);                               \
    aH0 = mfma16(ahi, whh_h[(c)][0], aH0);                                     \
    aH0 = mfma16(alo, whh_h[(c)][0], aH0);                                     \
    aH0 = mfma16(ahi, whh_l[(c)][0], aH0);                                     \
    aH1 = mfma16(ahi, whh_h[(c)][1], aH1);                                     \
    aH1 = mfma16(alo, whh_h[(c)][1], aH1);                                     \
    aH1 = mfma16(ahi, whh_l[(c)][1], aH1);                                     \
    if ((c) & 1) {                                                             \
      aO1 = mfma16(ahi, who[(c)], aO1);                                        \
      aO1 = mfma16(alo, who[(c)], aO1);                                        \
    } else {                                                                   \
      aO0 = mfma16(ahi, who[(c)], aO0);                                        \
      aO0 = mfma16(alo, who[(c)], aO0);                                        \
    }                                                                          \
  }

// bulk spin (epilogue only)
#define TAG_READ(PARITY, TEXP)                                                 \
  {                                                                            \
    const volatile u32x4* rp = (const volatile u32x4*)(                        \
        board + (PARITY) * 8192 + (tn & 7) * 1024 + kb0 + tq * 8);             \
    const unsigned int Texp = (unsigned int)(TEXP);                            \
    int iter = 0;                                                              \
    while (true) {                                                             \
      _Pragma("unroll")                                                        \
      for (int c = 0; c < 8; ++c) {                                            \
        q[2 * c]     = rp[c * 8];                                              \
        q[2 * c + 1] = rp[c * 8 + 1];                                          \
      }                                                                        \
      unsigned int bad = 0;                                                    \
      _Pragma("unroll")                                                        \
      for (int i = 0; i < 16; ++i) {                                           \
        u32x4 vq = q[i];                                                       \
        bad |= (vq[0] ^ Texp) | (vq[1] ^ Texp) | (vq[2] ^ Texp) | (vq[3] ^ Texp); \
      }                                                                        \
      if (__all((bad & 7u) == 0)) break;                                       \
      if (++iter > SPIN_LIM) { sh_dead = 1; break; }                           \
    }                                                                          \
  }

// Persistent RNN, 8 teams x 32 WGs (team = bid&7: placement-independent for
// correctness; XCD-local under round-robin dispatch as a perf hint).
// Team g: batch rows [8g,8g+8). WG r = bid>>3: h-cols [32r,32r+32), o-cols
// [16r,16r+16). Waves = K-quarters; weights register-resident (bf16 hi/lo).
// A-rows 8..15 mirror 0..7; duplicate C rows discarded by the tq<2 guard.
// ws: 8 team boards [2 parity][8 rows][1024] u32 = 512KB. No memset needed.
__global__ __launch_bounds__(256, 1)
void rnn_team(const float* __restrict__ x, const float* __restrict__ h0,
              const float* __restrict__ i_h, const float* __restrict__ h_h,
              const float* __restrict__ h_o, const float* __restrict__ b_i,
              const float* __restrict__ b_o, float* __restrict__ out,
              unsigned int* __restrict__ ws) {
  const int bid = blockIdx.x;
  const int g   = bid & 7;
  const int r   = bid >> 3;
  const int wv  = threadIdx.x >> 6, lane = threadIdx.x & 63;
  const int tn  = lane & 15, tq = lane >> 4;

  __shared__ int sh_dead;
  __shared__ float red_h[2][4][256];
  __shared__ float red_o[2][4][128];
  if (threadIdx.x == 0) sh_dead = 0;

  const int Jw  = r * 32;
  const int Ow  = r * 16;
  const int kb0 = wv * 256;
  const int xq0 = wv * 128;
  const int Bg  = g * 8;
  unsigned int* board = ws + g * 16384;

  // ---- register-resident weights (bf16 hi/lo) ----
  bf16x8 whh_h[8][2], whh_l[8][2], who[8], wih_h[4][2], wih_l[4][2];
#pragma unroll
  for (int c = 0; c < 8; ++c) {
    const int kb = kb0 + c * 32 + tq * 8;
#pragma unroll
    for (int nf = 0; nf < 2; ++nf)
#pragma unroll
      for (int j = 0; j < 8; ++j) {
        float v = h_h[(kb + j) * NH + Jw + nf * 16 + tn];
        __bf16 hi = (__bf16)v;
        whh_h[c][nf][j] = hi;
        whh_l[c][nf][j] = (__bf16)(v - (float)hi);
      }
#pragma unroll
    for (int j = 0; j < 8; ++j)
      who[c][j] = (__bf16)h_o[(kb + j) * NO + Ow + tn];
  }
#pragma unroll
  for (int c = 0; c < 4; ++c) {
    const int kb = xq0 + c * 32 + tq * 8;
#pragma unroll
    for (int nf = 0; nf < 2; ++nf)
#pragma unroll
      for (int j = 0; j < 8; ++j) {
        float v = i_h[(kb + j) * NH + Jw + nf * 16 + tn];
        __bf16 hi = (__bf16)v;
        wih_h[c][nf][j] = hi;
        wih_l[c][nf][j] = (__bf16)(v - (float)hi);
      }
  }

  const int prow = 2 * wv + (lane >> 5);
  const int pcol = lane & 31;
  const int orow = 2 * wv + ((lane >> 4) & 1);
  const int ocol = lane & 15;
  const float bi_p = b_i[Jw + pcol];
  const float bo_p = b_o[Ow + ocol];

  // two per-lane poll bases (parity 0/1), computed once
  const volatile u32x4* rp0 =
      (const volatile u32x4*)(board + (tn & 7) * 1024 + kb0 + tq * 8);
  const volatile u32x4* rp1 =
      (const volatile u32x4*)(board + 8192 + (tn & 7) * 1024 + kb0 + tq * 8);

  __syncthreads();  // sh_dead visible

  // x prefetch (one step ahead), mirrored rows (tn&7)
  f32x4 xn[8];
#pragma unroll
  for (int c = 0; c < 4; ++c) {
    const float* xp = x + (size_t)(Bg + (tn & 7)) * NIN + xq0 + c * 32 + tq * 8;
    xn[2 * c]     = *(const f32x4*)xp;
    xn[2 * c + 1] = *(const f32x4*)(xp + 4);
  }

  for (int t = 0; t < SEQ; ++t) {
    f32x4 aH0 = {0.f, 0.f, 0.f, 0.f}, aH1 = {0.f, 0.f, 0.f, 0.f};
    f32x4 aO0 = {0.f, 0.f, 0.f, 0.f}, aO1 = {0.f, 0.f, 0.f, 0.f};
    const volatile u32x4* rp = (t & 1) ? rp1 : rp0;

    // ---- issue board loads FIRST: fetch RT hides under xi MFMA below ----
    u32x4 q[16];
    if (t > 0) {
#pragma unroll
      for (int c = 0; c < 8; ++c) {
        q[2 * c]     = rp[c * 8];
        q[2 * c + 1] = rp[c * 8 + 1];
      }
    }

    // ---- xi = x_t @ W_ih from prefetched registers ----
#pragma unroll
    for (int c = 0; c < 4; ++c) {
      bf16x8 xhi, xlo;
#pragma unroll
      for (int e = 0; e < 4; ++e) {
        float f0 = xn[2 * c][e], f1 = xn[2 * c + 1][e];
        __bf16 h1 = (__bf16)f0; xhi[e] = h1; xlo[e] = (__bf16)(f0 - (float)h1);
        __bf16 h2 = (__bf16)f1; xhi[4 + e] = h2; xlo[4 + e] = (__bf16)(f1 - (float)h2);
      }
      aH0 = mfma16(xhi, wih_h[c][0], aH0);
      aH0 = mfma16(xlo, wih_h[c][0], aH0);
      aH0 = mfma16(xhi, wih_l[c][0], aH0);
      aH1 = mfma16(xhi, wih_h[c][1], aH1);
      aH1 = mfma16(xlo, wih_h[c][1], aH1);
      aH1 = mfma16(xhi, wih_l[c][1], aH1);
    }

    // issue next-step x loads now (consumed next iteration; hides under
    // straggler spins and the consume MFMAs)
    if (t + 1 < SEQ) {
#pragma unroll
      for (int c = 0; c < 4; ++c) {
        const float* xp = x + (size_t)((t + 1) * NB + Bg + (tn & 7)) * NIN +
                          xq0 + c * 32 + tq * 8;
        xn[2 * c]     = *(const f32x4*)xp;
        xn[2 * c + 1] = *(const f32x4*)(xp + 4);
      }
    }

    // ---- acquire + consume h_t ----
    if (t == 0) {
      // h_0 straight from input
#pragma unroll
      for (int c = 0; c < 8; ++c) {
        const float* hp =
            h0 + (size_t)(Bg + (tn & 7)) * NH + kb0 + c * 32 + tq * 8;
        f32x4 ha = *(const f32x4*)hp;
        f32x4 hb = *(const f32x4*)(hp + 4);
#pragma unroll
        for (int u = 0; u < 4; ++u) {
          float f0 = ha[u];
          __bf16 hi0 = (__bf16)f0;
          unsigned int hw0 = (unsigned int)__builtin_bit_cast(unsigned short, hi0);
          unsigned int lw0 = (unsigned int)__builtin_bit_cast(
              unsigned short, (__bf16)(f0 - (float)hi0));
          q[2 * c][u] = (hw0 << 16) | (lw0 & 0xFFF8u);
          float f1 = hb[u];
          __bf16 hi1 = (__bf16)f1;
          unsigned int hw1 = (unsigned int)__builtin_bit_cast(unsigned short, hi1);
          unsigned int lw1 = (unsigned int)__builtin_bit_cast(
              unsigned short, (__bf16)(f1 - (float)hi1));
          q[2 * c + 1][u] = (hw1 << 16) | (lw1 & 0xFFF8u);
        }
      }
#pragma unroll
      for (int c = 0; c < 8; ++c) CONSUME(c);
    } else {
      const unsigned int Texp = (unsigned int)((t + 2) & 7);
      bool dn[8];
      int npend = 0;
      // first pass on the pre-issued data: consume whatever is ready
#pragma unroll
      for (int c = 0; c < 8; ++c) {
        bool ok;
        CHUNK_CHECK(c, Texp, ok);
        dn[c] = ok;
        if (ok) { CONSUME(c); } else { ++npend; }
      }
      // spin only on pending chunks; consumes overlap stragglers' flight
      int iter = 0;
      while (npend > 0) {
#pragma unroll
        for (int c = 0; c < 8; ++c)
          if (!dn[c]) { q[2 * c] = rp[c * 8]; q[2 * c + 1] = rp[c * 8 + 1]; }
#pragma unroll
        for (int c = 0; c < 8; ++c)
          if (!dn[c]) {
            bool ok;
            CHUNK_CHECK(c, Texp, ok);
            if (ok) { CONSUME(c); dn[c] = true; --npend; }
          }
        if (++iter > SPIN_LIM) { sh_dead = 1; break; }
      }
    }
    f32x4 aO = aO0 + aO1;

    // ---- cross-wave K reduction (depth-2 LDS); rows 8..15 are mirrors ----
    const int par = t & 1;
    if (tq < 2) {
#pragma unroll
      for (int rr = 0; rr < 4; ++rr) {
        red_h[par][wv][(tq * 4 + rr) * 32 + tn]      = aH0[rr];
        red_h[par][wv][(tq * 4 + rr) * 32 + 16 + tn] = aH1[rr];
        red_o[par][wv][(tq * 4 + rr) * 16 + tn]      = aO[rr];
      }
    }
    __syncthreads();
    if (sh_dead) break;  // WG-uniform bail -> visible FAIL, no hang

    // ---- publish h_{t+1}: tanh -> pack(hi|lo|tag) -> agent atomic store ----
    float hs = 0.f;
#pragma unroll
    for (int s = 0; s < 4; ++s) hs += red_h[par][s][prow * 32 + pcol];
    float v = tanhf(hs + bi_p);
    __bf16 vh = (__bf16)v;
    unsigned int hb16 = (unsigned int)__builtin_bit_cast(unsigned short, vh);
    unsigned int lb16 = (unsigned int)__builtin_bit_cast(
        unsigned short, (__bf16)(v - (float)vh));
    unsigned int pk = (hb16 << 16) | (lb16 & 0xFFF8u) | ((t + 3u) & 7u);
    __hip_atomic_store(&board[((t + 1) & 1) * 8192 + prow * 1024 + Jw + pcol],
                       pk, __ATOMIC_RELAXED, __HIP_MEMORY_SCOPE_AGENT);

    // ---- off critical path: o_{t-1} and h_final ----
    if (lane < 32) {
      float os = 0.f;
#pragma unroll
      for (int s = 0; s < 4; ++s) os += red_o[par][s][orow * 16 + ocol];
      float o = os + bo_p;
      o = (o >= 0.f) ? o : 0.01f * o;
      if (t >= 1)
        out[((size_t)(t - 1) * NB + Bg + orow) * NO + Ow + ocol] = o;
    }
    if (t == SEQ - 1)
      out[(size_t)SEQ * NB * NO + (size_t)(Bg + prow) * NH + Jw + pcol] = v;
  }

  // ---- epilogue: o_{SEQ-1} from h_SEQ (parity 0, tag (SEQ+2)&7 = 2) ----
  if (!sh_dead) {
    u32x4 q[16];
    TAG_READ(0, (SEQ + 2) & 7);
    f32x4 aO0 = {0.f, 0.f, 0.f, 0.f}, aO1 = {0.f, 0.f, 0.f, 0.f};
#pragma unroll
    for (int c = 0; c < 8; ++c) {
      u32x4 a = q[2 * c], b = q[2 * c + 1];
      u32x4 hw, lw;
      hw[0] = (a[0] >> 16) | (a[1] & 0xFFFF0000u);
      hw[1] = (a[2] >> 16) | (a[3] & 0xFFFF0000u);
      hw[2] = (b[0] >> 16) | (b[1] & 0xFFFF0000u);
      hw[3] = (b[2] >> 16) | (b[3] & 0xFFFF0000u);
      lw[0] = ((a[0] & 0xFFFFu) | (a[1] << 16)) & 0xFFF8FFF8u;
      lw[1] = ((a[2] & 0xFFFFu) | (a[3] << 16)) & 0xFFF8FFF8u;
      lw[2] = ((b[0] & 0xFFFFu) | (b[1] << 16)) & 0xFFF8FFF8u;
      lw[3] = ((b[2] & 0xFFFFu) | (b[3] << 16)) & 0xFFF8FFF8u;
      bf16x8 ahi = __builtin_bit_cast(bf16x8, hw);
      bf16x8 alo = __builtin_bit_cast(bf16x8, lw);
      if (c & 1) {
        aO1 = mfma16(ahi, who[c], aO1);
        aO1 = mfma16(alo, who[c], aO1);
      } else {
        aO0 = mfma16(ahi, who[c], aO0);
        aO0 = mfma16(alo, who[c], aO0);
      }
    }
    f32x4 aO = aO0 + aO1;
    if (tq < 2) {
#pragma unroll
      for (int rr = 0; rr < 4; ++rr)
        red_o[0][wv][(tq * 4 + rr) * 16 + tn] = aO[rr];
    }
    __syncthreads();
    if (lane < 32 && !sh_dead) {
      float os = 0.f;
#pragma unroll
      for (int s = 0; s < 4; ++s) os += red_o[0][s][orow * 16 + ocol];
      float o = os + bo_p;
      o = (o >= 0.f) ? o : 0.01f * o;
      out[((size_t)(SEQ - 1) * NB + Bg + orow) * NO + Ow + ocol] = o;
    }
  }
}

extern "C" void kernel_launch(void* const* d_in, const int* in_sizes, int n_in,
                              void* d_out, int out_size, void* d_ws, size_t ws_size,
                              hipStream_t stream) {
  (void)in_sizes; (void)n_in; (void)out_size; (void)ws_size;
  const float* x   = (const float*)d_in[0];
  const float* h0  = (const float*)d_in[1];
  const float* i_h = (const float*)d_in[2];
  const float* h_h = (const float*)d_in[3];
  const float* h_o = (const float*)d_in[4];
  const float* b_i = (const float*)d_in[5];
  const float* b_o = (const float*)d_in[6];
  float* out = (float*)d_out;
  unsigned int* ws = (unsigned int*)d_ws;  // 512KB boards; poison/leftovers
                                           // self-reject via tags.

  void* args[] = {&x, &h0, &i_h, &h_h, &h_o, &b_i, &b_o, &out, &ws};
  hipError_t err = hipLaunchCooperativeKernel((const void*)rnn_team,
                                              dim3(256), dim3(256), args, 0, stream);
  if (err != hipSuccess) {
    rnn_team<<<dim3(256), dim3(256), 0, stream>>>(
        x, h0, i_h, h_h, h_o, b_i, b_o, out, ws);
  }
}

// Round 7
// 2849.774 us; speedup vs baseline: 1.1423x; 1.1423x over previous
//
#include <hip/hip_runtime.h>
#include <hip/hip_bf16.h>
#include <math.h>

#define SEQ 512
#define NB  64
#define NIN 512
#define NH  1024
#define NO  512

#define SPIN_LIM 20000  // bounded waits -> visible FAIL, never a watchdog hang

typedef __bf16 bf16x8 __attribute__((ext_vector_type(8)));
typedef float  f32x4  __attribute__((ext_vector_type(4)));
typedef unsigned int u32x4 __attribute__((ext_vector_type(4)));

__device__ __forceinline__ f32x4 mfma16(bf16x8 a, bf16x8 b, f32x4 c) {
  return __builtin_amdgcn_mfma_f32_16x16x32_bf16(a, b, c, 0, 0, 0);
}

// sc0 store: lands in the issuing XCD's L2 (fast local-visibility path).
__device__ __forceinline__ void st_sc0(unsigned int* p, unsigned int v) {
  asm volatile("global_store_dword %0, %1, off sc0" :: "v"(p), "v"(v) : "memory");
}

// ---- exchange: agent-scope tag-in-data (R5-PROVEN protocol) ----
// Board word = hi bf16 [31:16] | lo bf16 top-13 [15:3] | tag [2:0].
// tag(h_s) = (s+2)&7. Single-u32 atomicity => verify-before-consume on the
// exact registers consumed: no acks, no flags, no fences. Producer publishes
// DUAL: sc0 store (fast, local L2) then relaxed AGENT atomic (MALL backstop,
// the R5-proven visibility path) -- same value, so correct under any cache
// semantics / block placement; pure upside if consumers are co-XCD.
// Consumer: volatile loads re-issued per round; per-word tag validates
// per-word (tearing/stale/poison self-reject). Poison 0xAA (tag 2) rejects at
// first uses (t=1 expects 3, t=2 expects 4); depth-2 parity reuse is WAR-safe
// by full-team step gating (a WG publishes h_{t+1} only after consuming ALL
// of h_t into registers).
//
// R7 change: cheap SENTINEL poll rounds. A producer wave writes 2 rows x 32
// cols in ONE store instruction, and a consumer lane's 8 words of chunk c are
// 8 consecutive cols of one such row (one 32B span) -- so polling word 0 of
// each chunk (8 dwords/lane/round instead of 64) detects readiness with ~8x
// less broadcast bandwidth per retry round; the subsequent bulk read is then
// fully tag-verified before consume (bounded retry), preserving safety.

#define BULK_READ(rp)                                                          \
  _Pragma("unroll")                                                            \
  for (int c = 0; c < 8; ++c) {                                                \
    q[2 * c]     = (rp)[c * 8];                                                \
    q[2 * c + 1] = (rp)[c * 8 + 1];                                            \
  }

#define CHECK_ALL(TEXP, ok)                                                    \
  {                                                                            \
    unsigned int bad = 0;                                                      \
    _Pragma("unroll")                                                          \
    for (int i = 0; i < 16; ++i) {                                             \
      u32x4 vq = q[i];                                                         \
      bad |= (vq[0] ^ (TEXP)) | (vq[1] ^ (TEXP)) | (vq[2] ^ (TEXP)) |          \
             (vq[3] ^ (TEXP));                                                 \
    }                                                                          \
    ok = __all((bad & 7u) == 0);                                               \
  }

// bulk spin (epilogue + verify-retry path)
#define TAG_READ_LOOP(rp, TEXP)                                                \
  {                                                                            \
    int iter = 0;                                                              \
    while (true) {                                                             \
      BULK_READ(rp);                                                           \
      bool okk;                                                                \
      CHECK_ALL(TEXP, okk);                                                    \
      if (okk) break;                                                          \
      if (++iter > SPIN_LIM) { sh_dead = 1; break; }                           \
    }                                                                          \
  }

// Persistent RNN, 8 teams x 32 WGs (team = bid&7: placement-independent for
// correctness; XCD-local under round-robin dispatch as a perf hint).
// Team g: batch rows [8g,8g+8). WG r = bid>>3: h-cols [32r,32r+32), o-cols
// [16r,16r+16). Waves = K-quarters; weights register-resident (bf16 hi/lo).
// A-rows 8..15 mirror 0..7; duplicate C rows discarded by the tq<2 guard.
// ws: 8 team boards [2 parity][8 rows][1024] u32 = 512KB. No memset needed.
__global__ __launch_bounds__(256, 1)
void rnn_team(const float* __restrict__ x, const float* __restrict__ h0,
              const float* __restrict__ i_h, const float* __restrict__ h_h,
              const float* __restrict__ h_o, const float* __restrict__ b_i,
              const float* __restrict__ b_o, float* __restrict__ out,
              unsigned int* __restrict__ ws) {
  const int bid = blockIdx.x;
  const int g   = bid & 7;
  const int r   = bid >> 3;
  const int wv  = threadIdx.x >> 6, lane = threadIdx.x & 63;
  const int tn  = lane & 15, tq = lane >> 4;

  __shared__ int sh_dead;
  __shared__ float red_h[2][4][256];
  __shared__ float red_o[2][4][128];
  if (threadIdx.x == 0) sh_dead = 0;

  const int Jw  = r * 32;
  const int Ow  = r * 16;
  const int kb0 = wv * 256;
  const int xq0 = wv * 128;
  const int Bg  = g * 8;
  unsigned int* board = ws + g * 16384;

  // ---- register-resident weights (bf16 hi/lo) ----
  bf16x8 whh_h[8][2], whh_l[8][2], who[8], wih_h[4][2], wih_l[4][2];
#pragma unroll
  for (int c = 0; c < 8; ++c) {
    const int kb = kb0 + c * 32 + tq * 8;
#pragma unroll
    for (int nf = 0; nf < 2; ++nf)
#pragma unroll
      for (int j = 0; j < 8; ++j) {
        float v = h_h[(kb + j) * NH + Jw + nf * 16 + tn];
        __bf16 hi = (__bf16)v;
        whh_h[c][nf][j] = hi;
        whh_l[c][nf][j] = (__bf16)(v - (float)hi);
      }
#pragma unroll
    for (int j = 0; j < 8; ++j)
      who[c][j] = (__bf16)h_o[(kb + j) * NO + Ow + tn];
  }
#pragma unroll
  for (int c = 0; c < 4; ++c) {
    const int kb = xq0 + c * 32 + tq * 8;
#pragma unroll
    for (int nf = 0; nf < 2; ++nf)
#pragma unroll
      for (int j = 0; j < 8; ++j) {
        float v = i_h[(kb + j) * NH + Jw + nf * 16 + tn];
        __bf16 hi = (__bf16)v;
        wih_h[c][nf][j] = hi;
        wih_l[c][nf][j] = (__bf16)(v - (float)hi);
      }
  }

  const int prow = 2 * wv + (lane >> 5);
  const int pcol = lane & 31;
  const int orow = 2 * wv + ((lane >> 4) & 1);
  const int ocol = lane & 15;
  const float bi_p = b_i[Jw + pcol];
  const float bo_p = b_o[Ow + ocol];

  // two per-lane poll bases (parity 0/1), computed once
  const volatile u32x4* rp0 =
      (const volatile u32x4*)(board + (tn & 7) * 1024 + kb0 + tq * 8);
  const volatile u32x4* rp1 =
      (const volatile u32x4*)(board + 8192 + (tn & 7) * 1024 + kb0 + tq * 8);

  __syncthreads();  // sh_dead visible

  // x prefetch (one step ahead), mirrored rows (tn&7)
  f32x4 xn[8];
#pragma unroll
  for (int c = 0; c < 4; ++c) {
    const float* xp = x + (size_t)(Bg + (tn & 7)) * NIN + xq0 + c * 32 + tq * 8;
    xn[2 * c]     = *(const f32x4*)xp;
    xn[2 * c + 1] = *(const f32x4*)(xp + 4);
  }

  for (int t = 0; t < SEQ; ++t) {
    f32x4 aH0 = {0.f, 0.f, 0.f, 0.f}, aH1 = {0.f, 0.f, 0.f, 0.f};
    f32x4 aO0 = {0.f, 0.f, 0.f, 0.f}, aO1 = {0.f, 0.f, 0.f, 0.f};
    const volatile u32x4* rp = (t & 1) ? rp1 : rp0;

    // ---- xi = x_t @ W_ih from prefetched registers ----
#pragma unroll
    for (int c = 0; c < 4; ++c) {
      bf16x8 xhi, xlo;
#pragma unroll
      for (int e = 0; e < 4; ++e) {
        float f0 = xn[2 * c][e], f1 = xn[2 * c + 1][e];
        __bf16 h1 = (__bf16)f0; xhi[e] = h1; xlo[e] = (__bf16)(f0 - (float)h1);
        __bf16 h2 = (__bf16)f1; xhi[4 + e] = h2; xlo[4 + e] = (__bf16)(f1 - (float)h2);
      }
      aH0 = mfma16(xhi, wih_h[c][0], aH0);
      aH0 = mfma16(xlo, wih_h[c][0], aH0);
      aH0 = mfma16(xhi, wih_l[c][0], aH0);
      aH1 = mfma16(xhi, wih_h[c][1], aH1);
      aH1 = mfma16(xlo, wih_h[c][1], aH1);
      aH1 = mfma16(xhi, wih_l[c][1], aH1);
    }

    // ---- acquire h_t (h0 direct from input at t=0) ----
    u32x4 q[16];
    if (t == 0) {
#pragma unroll
      for (int c = 0; c < 8; ++c) {
        const float* hp =
            h0 + (size_t)(Bg + (tn & 7)) * NH + kb0 + c * 32 + tq * 8;
        f32x4 ha = *(const f32x4*)hp;
        f32x4 hb = *(const f32x4*)(hp + 4);
#pragma unroll
        for (int u = 0; u < 4; ++u) {
          float f0 = ha[u];
          __bf16 hi0 = (__bf16)f0;
          unsigned int hw0 = (unsigned int)__builtin_bit_cast(unsigned short, hi0);
          unsigned int lw0 = (unsigned int)__builtin_bit_cast(
              unsigned short, (__bf16)(f0 - (float)hi0));
          q[2 * c][u] = (hw0 << 16) | (lw0 & 0xFFF8u);
          float f1 = hb[u];
          __bf16 hi1 = (__bf16)f1;
          unsigned int hw1 = (unsigned int)__builtin_bit_cast(unsigned short, hi1);
          unsigned int lw1 = (unsigned int)__builtin_bit_cast(
              unsigned short, (__bf16)(f1 - (float)hi1));
          q[2 * c + 1][u] = (hw1 << 16) | (lw1 & 0xFFF8u);
        }
      }
    } else {
      const unsigned int Texp = (unsigned int)((t + 2) & 7);
      // fast path: one bulk read; usually already valid
      BULK_READ(rp);
      bool ok;
      CHECK_ALL(Texp, ok);
      if (!ok) {
        // cheap sentinel rounds: 8 dwords/lane (word 0 of each chunk)
        const volatile unsigned int* sp = (const volatile unsigned int*)rp;
        int iter = 0;
        while (true) {
          unsigned int bad = 0;
#pragma unroll
          for (int c = 0; c < 8; ++c) bad |= sp[c * 32] ^ Texp;
          if (__all((bad & 7u) == 0)) break;
          if (++iter > SPIN_LIM) { sh_dead = 1; break; }
        }
        // one verified bulk re-read (bounded retry; ~always 1 iteration)
        TAG_READ_LOOP(rp, Texp);
      }
    }

    // issue next-step x loads: latency hides under unpack+MFMA+reduce
    if (t + 1 < SEQ) {
#pragma unroll
      for (int c = 0; c < 4; ++c) {
        const float* xp = x + (size_t)((t + 1) * NB + Bg + (tn & 7)) * NIN +
                          xq0 + c * 32 + tq * 8;
        xn[2 * c]     = *(const f32x4*)xp;
        xn[2 * c + 1] = *(const f32x4*)(xp + 4);
      }
    }

    // ---- unpack (hi|lo planes) + MFMA ----
#pragma unroll
    for (int c = 0; c < 8; ++c) {
      u32x4 a = q[2 * c], b = q[2 * c + 1];
      u32x4 hw, lw;
      hw[0] = (a[0] >> 16) | (a[1] & 0xFFFF0000u);
      hw[1] = (a[2] >> 16) | (a[3] & 0xFFFF0000u);
      hw[2] = (b[0] >> 16) | (b[1] & 0xFFFF0000u);
      hw[3] = (b[2] >> 16) | (b[3] & 0xFFFF0000u);
      lw[0] = ((a[0] & 0xFFFFu) | (a[1] << 16)) & 0xFFF8FFF8u;
      lw[1] = ((a[2] & 0xFFFFu) | (a[3] << 16)) & 0xFFF8FFF8u;
      lw[2] = ((b[0] & 0xFFFFu) | (b[1] << 16)) & 0xFFF8FFF8u;
      lw[3] = ((b[2] & 0xFFFFu) | (b[3] << 16)) & 0xFFF8FFF8u;
      bf16x8 ahi = __builtin_bit_cast(bf16x8, hw);
      bf16x8 alo = __builtin_bit_cast(bf16x8, lw);
      aH0 = mfma16(ahi, whh_h[c][0], aH0);
      aH0 = mfma16(alo, whh_h[c][0], aH0);
      aH0 = mfma16(ahi, whh_l[c][0], aH0);
      aH1 = mfma16(ahi, whh_h[c][1], aH1);
      aH1 = mfma16(alo, whh_h[c][1], aH1);
      aH1 = mfma16(ahi, whh_l[c][1], aH1);
      if (c & 1) {
        aO1 = mfma16(ahi, who[c], aO1);
        aO1 = mfma16(alo, who[c], aO1);
      } else {
        aO0 = mfma16(ahi, who[c], aO0);
        aO0 = mfma16(alo, who[c], aO0);
      }
    }
    f32x4 aO = aO0 + aO1;

    // ---- cross-wave K reduction (depth-2 LDS); rows 8..15 are mirrors ----
    const int par = t & 1;
    if (tq < 2) {
#pragma unroll
      for (int rr = 0; rr < 4; ++rr) {
        red_h[par][wv][(tq * 4 + rr) * 32 + tn]      = aH0[rr];
        red_h[par][wv][(tq * 4 + rr) * 32 + 16 + tn] = aH1[rr];
        red_o[par][wv][(tq * 4 + rr) * 16 + tn]      = aO[rr];
      }
    }
    __syncthreads();
    if (sh_dead) break;  // WG-uniform bail -> visible FAIL, no hang

    // ---- publish h_{t+1}: tanh -> pack(hi|lo|tag) -> DUAL store ----
    float hs = 0.f;
#pragma unroll
    for (int s = 0; s < 4; ++s) hs += red_h[par][s][prow * 32 + pcol];
    float v = tanhf(hs + bi_p);
    __bf16 vh = (__bf16)v;
    unsigned int hb16 = (unsigned int)__builtin_bit_cast(unsigned short, vh);
    unsigned int lb16 = (unsigned int)__builtin_bit_cast(
        unsigned short, (__bf16)(v - (float)vh));
    unsigned int pk = (hb16 << 16) | (lb16 & 0xFFF8u) | ((t + 3u) & 7u);
    unsigned int* pub = &board[((t + 1) & 1) * 8192 + prow * 1024 + Jw + pcol];
    st_sc0(pub, pk);  // fast local-L2 visibility (same value; pure upside)
    __hip_atomic_store(pub, pk, __ATOMIC_RELAXED, __HIP_MEMORY_SCOPE_AGENT);

    // ---- off critical path: o_{t-1} and h_final ----
    if (lane < 32) {
      float os = 0.f;
#pragma unroll
      for (int s = 0; s < 4; ++s) os += red_o[par][s][orow * 16 + ocol];
      float o = os + bo_p;
      o = (o >= 0.f) ? o : 0.01f * o;
      if (t >= 1)
        out[((size_t)(t - 1) * NB + Bg + orow) * NO + Ow + ocol] = o;
    }
    if (t == SEQ - 1)
      out[(size_t)SEQ * NB * NO + (size_t)(Bg + prow) * NH + Jw + pcol] = v;
  }

  // ---- epilogue: o_{SEQ-1} from h_SEQ (parity 0, tag (SEQ+2)&7 = 2) ----
  if (!sh_dead) {
    u32x4 q[16];
    const unsigned int Texp = (unsigned int)((SEQ + 2) & 7);
    TAG_READ_LOOP(rp0, Texp);
    f32x4 aO0 = {0.f, 0.f, 0.f, 0.f}, aO1 = {0.f, 0.f, 0.f, 0.f};
#pragma unroll
    for (int c = 0; c < 8; ++c) {
      u32x4 a = q[2 * c], b = q[2 * c + 1];
      u32x4 hw, lw;
      hw[0] = (a[0] >> 16) | (a[1] & 0xFFFF0000u);
      hw[1] = (a[2] >> 16) | (a[3] & 0xFFFF0000u);
      hw[2] = (b[0] >> 16) | (b[1] & 0xFFFF0000u);
      hw[3] = (b[2] >> 16) | (b[3] & 0xFFFF0000u);
      lw[0] = ((a[0] & 0xFFFFu) | (a[1] << 16)) & 0xFFF8FFF8u;
      lw[1] = ((a[2] & 0xFFFFu) | (a[3] << 16)) & 0xFFF8FFF8u;
      lw[2] = ((b[0] & 0xFFFFu) | (b[1] << 16)) & 0xFFF8FFF8u;
      lw[3] = ((b[2] & 0xFFFFu) | (b[3] << 16)) & 0xFFF8FFF8u;
      bf16x8 ahi = __builtin_bit_cast(bf16x8, hw);
      bf16x8 alo = __builtin_bit_cast(bf16x8, lw);
      if (c & 1) {
        aO1 = mfma16(ahi, who[c], aO1);
        aO1 = mfma16(alo, who[c], aO1);
      } else {
        aO0 = mfma16(ahi, who[c], aO0);
        aO0 = mfma16(alo, who[c], aO0);
      }
    }
    f32x4 aO = aO0 + aO1;
    if (tq < 2) {
#pragma unroll
      for (int rr = 0; rr < 4; ++rr)
        red_o[0][wv][(tq * 4 + rr) * 16 + tn] = aO[rr];
    }
    __syncthreads();
    if (lane < 32 && !sh_dead) {
      float os = 0.f;
#pragma unroll
      for (int s = 0; s < 4; ++s) os += red_o[0][s][orow * 16 + ocol];
      float o = os + bo_p;
      o = (o >= 0.f) ? o : 0.01f * o;
      out[((size_t)(SEQ - 1) * NB + Bg + orow) * NO + Ow + ocol] = o;
    }
  }
}

extern "C" void kernel_launch(void* const* d_in, const int* in_sizes, int n_in,
                              void* d_out, int out_size, void* d_ws, size_t ws_size,
                              hipStream_t stream) {
  (void)in_sizes; (void)n_in; (void)out_size; (void)ws_size;
  const float* x   = (const float*)d_in[0];
  const float* h0  = (const float*)d_in[1];
  const float* i_h = (const float*)d_in[2];
  const float* h_h = (const float*)d_in[3];
  const float* h_o = (const float*)d_in[4];
  const float* b_i = (const float*)d_in[5];
  const float* b_o = (const float*)d_in[6];
  float* out = (float*)d_out;
  unsigned int* ws = (unsigned int*)d_ws;  // 512KB boards; poison/leftovers
                                           // self-reject via tags.

  void* args[] = {&x, &h0, &i_h, &h_h, &h_o, &b_i, &b_o, &out, &ws};
  hipError_t err = hipLaunchCooperativeKernel((const void*)rnn_team,
                                              dim3(256), dim3(256), args, 0, stream);
  if (err != hipSuccess) {
    rnn_team<<<dim3(256), dim3(256), 0, stream>>>(
        x, h0, i_h, h_h, h_o, b_i, b_o, out, ws);
  }
}

// Round 8
// 2156.589 us; speedup vs baseline: 1.5094x; 1.3214x over previous
//
#include <hip/hip_runtime.h>
#include <hip/hip_bf16.h>
#include <math.h>

#define SEQ 512
#define NB  64
#define NIN 512
#define NH  1024
#define NO  512

#define SPIN_LIM 20000  // bounded waits -> visible FAIL, never a watchdog hang

typedef __bf16 bf16x8 __attribute__((ext_vector_type(8)));
typedef float  f32x4  __attribute__((ext_vector_type(4)));
typedef unsigned int u32x4 __attribute__((ext_vector_type(4)));

__device__ __forceinline__ f32x4 mfma16(bf16x8 a, bf16x8 b, f32x4 c) {
  return __builtin_amdgcn_mfma_f32_16x16x32_bf16(a, b, c, 0, 0, 0);
}

// sc1 load: bypass L1/L2, service at the device coherence point (MALL).
// THE R8 FIX: plain/volatile poll loads can legally hit a STALE CLEAN copy in
// the local (non-cross-coherent) XCD L2; progress then waits on capacity
// eviction, not on the producer's store. sc1 makes every poll round a true
// MALL read -> detect latency becomes RT-bound (~0.5us), not eviction-bound.
__device__ __forceinline__ void ld4_sc1(u32x4& d, const unsigned int* p) {
  asm volatile("global_load_dwordx4 %0, %1, off sc1" : "=v"(d) : "v"(p));
}

// ---- exchange: agent-scope tag-in-data (R5-PROVEN protocol) ----
// Board word = hi bf16 [31:16] | lo bf16 top-13 [15:3] | tag [2:0].
// tag(h_s) = (s+2)&7. Single-u32 atomicity => verify-before-consume on the
// exact registers consumed: no acks, no flags, no fences. Producer: relaxed
// AGENT atomic store (write-through to MALL; proven cross-XCD visible in
// R0/R1/R5). Consumer: sc1 bulk read + tag check per round (per-word
// tearing/stale/poison self-reject). Poison 0xAA (tag 2) rejects at first
// uses (t=1 expects 3, t=2 expects 4); depth-2 parity reuse is WAR-safe by
// full-team step gating (a WG publishes h_{t+1} only after consuming ALL of
// h_t into registers).

#define BULK_READ_SC1(rp)                                                      \
  {                                                                            \
    _Pragma("unroll")                                                          \
    for (int c = 0; c < 8; ++c) {                                              \
      ld4_sc1(q[2 * c],     (rp) + c * 32);                                    \
      ld4_sc1(q[2 * c + 1], (rp) + c * 32 + 4);                                \
    }                                                                          \
    asm volatile("s_waitcnt vmcnt(0)" ::: "memory");                           \
    __builtin_amdgcn_sched_barrier(0);                                         \
  }

#define CHECK_ALL(TEXP, ok)                                                    \
  {                                                                            \
    unsigned int bad = 0;                                                      \
    _Pragma("unroll")                                                          \
    for (int i = 0; i < 16; ++i) {                                             \
      u32x4 vq = q[i];                                                         \
      bad |= (vq[0] ^ (TEXP)) | (vq[1] ^ (TEXP)) | (vq[2] ^ (TEXP)) |          \
             (vq[3] ^ (TEXP));                                                 \
    }                                                                          \
    ok = __all((bad & 7u) == 0);                                               \
  }

#define TAG_READ_LOOP(rp, TEXP)                                                \
  {                                                                            \
    int iter = 0;                                                              \
    while (true) {                                                             \
      BULK_READ_SC1(rp);                                                       \
      bool okk;                                                                \
      CHECK_ALL(TEXP, okk);                                                    \
      if (okk) break;                                                          \
      if (++iter > SPIN_LIM) { sh_dead = 1; break; }                           \
    }                                                                          \
  }

// Persistent RNN, 8 teams x 32 WGs (team = bid&7: placement-independent for
// correctness; XCD-local under round-robin dispatch as a perf hint).
// Team g: batch rows [8g,8g+8). WG r = bid>>3: h-cols [32r,32r+32), o-cols
// [16r,16r+16). Waves = K-quarters; weights register-resident (bf16 hi/lo).
// A-rows 8..15 mirror 0..7; duplicate C rows discarded by the tq<2 guard.
// ws: 8 team boards [2 parity][8 rows][1024] u32 = 512KB. No memset needed.
__global__ __launch_bounds__(256, 1)
void rnn_team(const float* __restrict__ x, const float* __restrict__ h0,
              const float* __restrict__ i_h, const float* __restrict__ h_h,
              const float* __restrict__ h_o, const float* __restrict__ b_i,
              const float* __restrict__ b_o, float* __restrict__ out,
              unsigned int* __restrict__ ws) {
  const int bid = blockIdx.x;
  const int g   = bid & 7;
  const int r   = bid >> 3;
  const int wv  = threadIdx.x >> 6, lane = threadIdx.x & 63;
  const int tn  = lane & 15, tq = lane >> 4;

  __shared__ int sh_dead;
  __shared__ float red_h[2][4][256];
  __shared__ float red_o[2][4][128];
  if (threadIdx.x == 0) sh_dead = 0;

  const int Jw  = r * 32;
  const int Ow  = r * 16;
  const int kb0 = wv * 256;
  const int xq0 = wv * 128;
  const int Bg  = g * 8;
  unsigned int* board = ws + g * 16384;

  // ---- register-resident weights (bf16 hi/lo) ----
  bf16x8 whh_h[8][2], whh_l[8][2], who[8], wih_h[4][2], wih_l[4][2];
#pragma unroll
  for (int c = 0; c < 8; ++c) {
    const int kb = kb0 + c * 32 + tq * 8;
#pragma unroll
    for (int nf = 0; nf < 2; ++nf)
#pragma unroll
      for (int j = 0; j < 8; ++j) {
        float v = h_h[(kb + j) * NH + Jw + nf * 16 + tn];
        __bf16 hi = (__bf16)v;
        whh_h[c][nf][j] = hi;
        whh_l[c][nf][j] = (__bf16)(v - (float)hi);
      }
#pragma unroll
    for (int j = 0; j < 8; ++j)
      who[c][j] = (__bf16)h_o[(kb + j) * NO + Ow + tn];
  }
#pragma unroll
  for (int c = 0; c < 4; ++c) {
    const int kb = xq0 + c * 32 + tq * 8;
#pragma unroll
    for (int nf = 0; nf < 2; ++nf)
#pragma unroll
      for (int j = 0; j < 8; ++j) {
        float v = i_h[(kb + j) * NH + Jw + nf * 16 + tn];
        __bf16 hi = (__bf16)v;
        wih_h[c][nf][j] = hi;
        wih_l[c][nf][j] = (__bf16)(v - (float)hi);
      }
  }

  const int prow = 2 * wv + (lane >> 5);
  const int pcol = lane & 31;
  const int orow = 2 * wv + ((lane >> 4) & 1);
  const int ocol = lane & 15;
  const float bi_p = b_i[Jw + pcol];
  const float bo_p = b_o[Ow + ocol];

  // per-lane poll bases (parity 0/1), u32 element offsets
  const unsigned int* rp0 = board + (tn & 7) * 1024 + kb0 + tq * 8;
  const unsigned int* rp1 = rp0 + 8192;

  __syncthreads();  // sh_dead visible

  // x prefetch (one step ahead), mirrored rows (tn&7)
  f32x4 xn[8];
#pragma unroll
  for (int c = 0; c < 4; ++c) {
    const float* xp = x + (size_t)(Bg + (tn & 7)) * NIN + xq0 + c * 32 + tq * 8;
    xn[2 * c]     = *(const f32x4*)xp;
    xn[2 * c + 1] = *(const f32x4*)(xp + 4);
  }

  for (int t = 0; t < SEQ; ++t) {
    f32x4 aH0 = {0.f, 0.f, 0.f, 0.f}, aH1 = {0.f, 0.f, 0.f, 0.f};
    f32x4 aO0 = {0.f, 0.f, 0.f, 0.f}, aO1 = {0.f, 0.f, 0.f, 0.f};
    const unsigned int* rp = (t & 1) ? rp1 : rp0;

    // ---- xi = x_t @ W_ih from prefetched registers ----
#pragma unroll
    for (int c = 0; c < 4; ++c) {
      bf16x8 xhi, xlo;
#pragma unroll
      for (int e = 0; e < 4; ++e) {
        float f0 = xn[2 * c][e], f1 = xn[2 * c + 1][e];
        __bf16 h1 = (__bf16)f0; xhi[e] = h1; xlo[e] = (__bf16)(f0 - (float)h1);
        __bf16 h2 = (__bf16)f1; xhi[4 + e] = h2; xlo[4 + e] = (__bf16)(f1 - (float)h2);
      }
      aH0 = mfma16(xhi, wih_h[c][0], aH0);
      aH0 = mfma16(xlo, wih_h[c][0], aH0);
      aH0 = mfma16(xhi, wih_l[c][0], aH0);
      aH1 = mfma16(xhi, wih_h[c][1], aH1);
      aH1 = mfma16(xlo, wih_h[c][1], aH1);
      aH1 = mfma16(xhi, wih_l[c][1], aH1);
    }

    // ---- acquire h_t: sc1 tag-poll (h0 direct from input at t=0) ----
    u32x4 q[16];
    if (t == 0) {
#pragma unroll
      for (int c = 0; c < 8; ++c) {
        const float* hp =
            h0 + (size_t)(Bg + (tn & 7)) * NH + kb0 + c * 32 + tq * 8;
        f32x4 ha = *(const f32x4*)hp;
        f32x4 hb = *(const f32x4*)(hp + 4);
#pragma unroll
        for (int u = 0; u < 4; ++u) {
          float f0 = ha[u];
          __bf16 hi0 = (__bf16)f0;
          unsigned int hw0 = (unsigned int)__builtin_bit_cast(unsigned short, hi0);
          unsigned int lw0 = (unsigned int)__builtin_bit_cast(
              unsigned short, (__bf16)(f0 - (float)hi0));
          q[2 * c][u] = (hw0 << 16) | (lw0 & 0xFFF8u);
          float f1 = hb[u];
          __bf16 hi1 = (__bf16)f1;
          unsigned int hw1 = (unsigned int)__builtin_bit_cast(unsigned short, hi1);
          unsigned int lw1 = (unsigned int)__builtin_bit_cast(
              unsigned short, (__bf16)(f1 - (float)hi1));
          q[2 * c + 1][u] = (hw1 << 16) | (lw1 & 0xFFF8u);
        }
      }
    } else {
      const unsigned int Texp = (unsigned int)((t + 2) & 7);
      TAG_READ_LOOP(rp, Texp);
    }

    // issue next-step x loads: latency hides under unpack+MFMA+reduce
    if (t + 1 < SEQ) {
#pragma unroll
      for (int c = 0; c < 4; ++c) {
        const float* xp = x + (size_t)((t + 1) * NB + Bg + (tn & 7)) * NIN +
                          xq0 + c * 32 + tq * 8;
        xn[2 * c]     = *(const f32x4*)xp;
        xn[2 * c + 1] = *(const f32x4*)(xp + 4);
      }
    }

    // ---- unpack (hi|lo planes) + MFMA ----
#pragma unroll
    for (int c = 0; c < 8; ++c) {
      u32x4 a = q[2 * c], b = q[2 * c + 1];
      u32x4 hw, lw;
      hw[0] = (a[0] >> 16) | (a[1] & 0xFFFF0000u);
      hw[1] = (a[2] >> 16) | (a[3] & 0xFFFF0000u);
      hw[2] = (b[0] >> 16) | (b[1] & 0xFFFF0000u);
      hw[3] = (b[2] >> 16) | (b[3] & 0xFFFF0000u);
      lw[0] = ((a[0] & 0xFFFFu) | (a[1] << 16)) & 0xFFF8FFF8u;
      lw[1] = ((a[2] & 0xFFFFu) | (a[3] << 16)) & 0xFFF8FFF8u;
      lw[2] = ((b[0] & 0xFFFFu) | (b[1] << 16)) & 0xFFF8FFF8u;
      lw[3] = ((b[2] & 0xFFFFu) | (b[3] << 16)) & 0xFFF8FFF8u;
      bf16x8 ahi = __builtin_bit_cast(bf16x8, hw);
      bf16x8 alo = __builtin_bit_cast(bf16x8, lw);
      aH0 = mfma16(ahi, whh_h[c][0], aH0);
      aH0 = mfma16(alo, whh_h[c][0], aH0);
      aH0 = mfma16(ahi, whh_l[c][0], aH0);
      aH1 = mfma16(ahi, whh_h[c][1], aH1);
      aH1 = mfma16(alo, whh_h[c][1], aH1);
      aH1 = mfma16(ahi, whh_l[c][1], aH1);
      if (c & 1) {
        aO1 = mfma16(ahi, who[c], aO1);
        aO1 = mfma16(alo, who[c], aO1);
      } else {
        aO0 = mfma16(ahi, who[c], aO0);
        aO0 = mfma16(alo, who[c], aO0);
      }
    }
    f32x4 aO = aO0 + aO1;

    // ---- cross-wave K reduction (depth-2 LDS); rows 8..15 are mirrors ----
    const int par = t & 1;
    if (tq < 2) {
#pragma unroll
      for (int rr = 0; rr < 4; ++rr) {
        red_h[par][wv][(tq * 4 + rr) * 32 + tn]      = aH0[rr];
        red_h[par][wv][(tq * 4 + rr) * 32 + 16 + tn] = aH1[rr];
        red_o[par][wv][(tq * 4 + rr) * 16 + tn]      = aO[rr];
      }
    }
    __syncthreads();
    if (sh_dead) break;  // WG-uniform bail -> visible FAIL, no hang

    // ---- publish h_{t+1}: tanh -> pack(hi|lo|tag) -> agent atomic store ----
    float hs = 0.f;
#pragma unroll
    for (int s = 0; s < 4; ++s) hs += red_h[par][s][prow * 32 + pcol];
    float v = tanhf(hs + bi_p);
    __bf16 vh = (__bf16)v;
    unsigned int hb16 = (unsigned int)__builtin_bit_cast(unsigned short, vh);
    unsigned int lb16 = (unsigned int)__builtin_bit_cast(
        unsigned short, (__bf16)(v - (float)vh));
    unsigned int pk = (hb16 << 16) | (lb16 & 0xFFF8u) | ((t + 3u) & 7u);
    __hip_atomic_store(&board[((t + 1) & 1) * 8192 + prow * 1024 + Jw + pcol],
                       pk, __ATOMIC_RELAXED, __HIP_MEMORY_SCOPE_AGENT);

    // ---- off critical path: o_{t-1} and h_final ----
    if (lane < 32) {
      float os = 0.f;
#pragma unroll
      for (int s = 0; s < 4; ++s) os += red_o[par][s][orow * 16 + ocol];
      float o = os + bo_p;
      o = (o >= 0.f) ? o : 0.01f * o;
      if (t >= 1)
        out[((size_t)(t - 1) * NB + Bg + orow) * NO + Ow + ocol] = o;
    }
    if (t == SEQ - 1)
      out[(size_t)SEQ * NB * NO + (size_t)(Bg + prow) * NH + Jw + pcol] = v;
  }

  // ---- epilogue: o_{SEQ-1} from h_SEQ (parity 0, tag (SEQ+2)&7 = 2) ----
  if (!sh_dead) {
    u32x4 q[16];
    const unsigned int Texp = (unsigned int)((SEQ + 2) & 7);
    TAG_READ_LOOP(rp0, Texp);
    f32x4 aO0 = {0.f, 0.f, 0.f, 0.f}, aO1 = {0.f, 0.f, 0.f, 0.f};
#pragma unroll
    for (int c = 0; c < 8; ++c) {
      u32x4 a = q[2 * c], b = q[2 * c + 1];
      u32x4 hw, lw;
      hw[0] = (a[0] >> 16) | (a[1] & 0xFFFF0000u);
      hw[1] = (a[2] >> 16) | (a[3] & 0xFFFF0000u);
      hw[2] = (b[0] >> 16) | (b[1] & 0xFFFF0000u);
      hw[3] = (b[2] >> 16) | (b[3] & 0xFFFF0000u);
      lw[0] = ((a[0] & 0xFFFFu) | (a[1] << 16)) & 0xFFF8FFF8u;
      lw[1] = ((a[2] & 0xFFFFu) | (a[3] << 16)) & 0xFFF8FFF8u;
      lw[2] = ((b[0] & 0xFFFFu) | (b[1] << 16)) & 0xFFF8FFF8u;
      lw[3] = ((b[2] & 0xFFFFu) | (b[3] << 16)) & 0xFFF8FFF8u;
      bf16x8 ahi = __builtin_bit_cast(bf16x8, hw);
      bf16x8 alo = __builtin_bit_cast(bf16x8, lw);
      if (c & 1) {
        aO1 = mfma16(ahi, who[c], aO1);
        aO1 = mfma16(alo, who[c], aO1);
      } else {
        aO0 = mfma16(ahi, who[c], aO0);
        aO0 = mfma16(alo, who[c], aO0);
      }
    }
    f32x4 aO = aO0 + aO1;
    if (tq < 2) {
#pragma unroll
      for (int rr = 0; rr < 4; ++rr)
        red_o[0][wv][(tq * 4 + rr) * 16 + tn] = aO[rr];
    }
    __syncthreads();
    if (lane < 32 && !sh_dead) {
      float os = 0.f;
#pragma unroll
      for (int s = 0; s < 4; ++s) os += red_o[0][s][orow * 16 + ocol];
      float o = os + bo_p;
      o = (o >= 0.f) ? o : 0.01f * o;
      out[((size_t)(SEQ - 1) * NB + Bg + orow) * NO + Ow + ocol] = o;
    }
  }
}

extern "C" void kernel_launch(void* const* d_in, const int* in_sizes, int n_in,
                              void* d_out, int out_size, void* d_ws, size_t ws_size,
                              hipStream_t stream) {
  (void)in_sizes; (void)n_in; (void)out_size; (void)ws_size;
  const float* x   = (const float*)d_in[0];
  const float* h0  = (const float*)d_in[1];
  const float* i_h = (const float*)d_in[2];
  const float* h_h = (const float*)d_in[3];
  const float* h_o = (const float*)d_in[4];
  const float* b_i = (const float*)d_in[5];
  const float* b_o = (const float*)d_in[6];
  float* out = (float*)d_out;
  unsigned int* ws = (unsigned int*)d_ws;  // 512KB boards; poison/leftovers
                                           // self-reject via tags.

  void* args[] = {&x, &h0, &i_h, &h_h, &h_o, &b_i, &b_o, &out, &ws};
  hipError_t err = hipLaunchCooperativeKernel((const void*)rnn_team,
                                              dim3(256), dim3(256), args, 0, stream);
  if (err != hipSuccess) {
    rnn_team<<<dim3(256), dim3(256), 0, stream>>>(
        x, h0, i_h, h_h, h_o, b_i, b_o, out, ws);
  }
}